// Round 4
// baseline (247.843 us; speedup 1.0000x reference)
//
#include <hip/hip_runtime.h>
#include <float.h>

#define KCODES 512
#define GDIM 64
#define SBIAS 96.0f     // s = e2+96-2*x.w > 0 needs x.w < 58 (=12.7 sigma) -> safe; s < 256
#define TAUQ 0.015f     // quantized-gap flag threshold: covers 2*errA(~3e-3) + key step (2^-7)

typedef __attribute__((ext_vector_type(8))) short short8;   // 8 bf16 = 4 VGPR
typedef __attribute__((ext_vector_type(4))) float floatx4;  // MFMA C/D

// ---- workspace layout (float-index units) ----
// embT   f32[512*64]     [0, 32768)        original w, code-major
// e2     f32[512]        [32768, 33280)
// e2d    f64[512]        [33280, 34304)    (byte 133120, 8-aligned)
// emb_hi bf16[512*64]    [34304, 50688)    split of (-2*w), code-major
// emb_lo bf16[512*64]    [50688, 67072)

__device__ __forceinline__ void bf16split(float x, short& hi, short& lo) {
    unsigned u = __float_as_uint(x);
    unsigned h = (u + 0x7fffu + ((u >> 16) & 1u)) >> 16;   // RNE to bf16
    hi = (short)h;
    float hf = __uint_as_float(h << 16);
    float l = x - hf;                                      // exact in f32
    unsigned ul = __float_as_uint(l);
    lo = (short)((ul + 0x7fffu + ((ul >> 16) & 1u)) >> 16);
}

__device__ __forceinline__ void gload_lds16(const void* g, void* l) {
    __builtin_amdgcn_global_load_lds(
        (const __attribute__((address_space(1))) void*)g,
        (__attribute__((address_space(3))) void*)l, 16, 0, 0);
}

// 128 blocks x 256 = 512 waves: wave k preps code k (lane = dim g).
// emb_hi/lo store split of (-2*w): exact x(-2) scaling folds the -2 into the
// MFMA so the epilogue has no per-candidate fma (C is preloaded with e2+96).
__launch_bounds__(256)
__global__ void prep_kernel(const float* __restrict__ w,
                            float* __restrict__ embT,
                            float* __restrict__ e2,
                            double* __restrict__ e2d,
                            short* __restrict__ emb_hi,
                            short* __restrict__ emb_lo) {
    int t = blockIdx.x * 256 + threadIdx.x;   // 0..32767
    int k = t >> 6;                            // code (wave-uniform)
    int g = t & 63;                            // dim  (lane)
    float v = w[(size_t)g * KCODES + k];
    embT[(size_t)k * GDIM + g] = v;            // lane-contiguous store
    short h, l; bf16split(-2.0f * v, h, l);
    emb_hi[(size_t)k * GDIM + g] = h;
    emb_lo[(size_t)k * GDIM + g] = l;
    float s = v * v;
    double sd = (double)v * (double)v;
#pragma unroll
    for (int off = 32; off > 0; off >>= 1) {
        s  += __shfl_xor(s, off, 64);
        sd += __shfl_xor(sd, off, 64);
    }
    if (g == 0) { e2[k] = s; e2d[k] = sd; }
}

// Fused pass A + exact fix.  2048 blocks x 256 threads; launch_bounds(256,5)
// caps VGPR at 102 -> 5 waves/SIMD; chunk=32 cuts LDS to ~21KB -> 5 blocks/CU
// (round-3 evidence: perf tracks residency; was 4-block cap, ~1.3 measured).
// 512 codes in 16 chunks of 32, double-buffered global_load_lds DMA with the
// XOR-granule swizzle applied on the pre-swizzled GLOBAL source (dest linear).
// Codebook = -2w (split bf16); MFMA C preloaded with e2+96  =>  s = acc > 0.
// Packed-key argmin: key = (bits(s) & ~511) | n  (s>0 -> u32-order == s-order;
// quant step <= 2^-7). best = min_u32; sec via min/max (umed3 pattern); arg is
// free in the low 9 bits.  Ties/near-ties (recon gap <= TAUQ) -> LDS flag list;
// block tail reranks them in f64 (lexicographic (s,k)) — no extra dispatch.
__launch_bounds__(256, 5)
__global__ void vq_kernel(const float* __restrict__ x,
                          const float* __restrict__ embT,
                          const float* __restrict__ e2,
                          const double* __restrict__ e2d,
                          const short* __restrict__ emb_hi,
                          const short* __restrict__ emb_lo,
                          float* __restrict__ out_res,
                          float* __restrict__ out_arg) {
    __shared__ short s_hi[2][32 * 64];
    __shared__ short s_lo[2][32 * 64];
    __shared__ float s_e2[512];
    __shared__ int   s_arg[128];
    __shared__ float s_fixx[4][64];
    __shared__ int   s_flags[128];
    __shared__ int   s_nflag;

    const int t = threadIdx.x;
    const int wid = t >> 6;
    const int lane = t & 63;
    const int q = lane >> 4;          // quad
    const int c = lane & 15;          // col within tile
    const int blk = blockIdx.x;
    const int grp = blk >> 9;                          // 512 blocks per group
    const int posbase = ((blk & 511) << 7) + wid * 32; // wave's 32 positions
    const int b = posbase >> 10;
    const int hwb = posbase & 1023;

    if (t == 0) s_nflag = 0;

    // DMA geometry (chunk = 32 rows x 64 shorts = 4KB/array): wave wid owns
    // rows wid*8..wid*8+8 = 1KB = 64 lanes x 16B -> ONE gload_lds16 per array.
    // row r = wid*8 + (lane>>3); swizzled granule u = (lane&7) ^ (r&7).
    const int rA = wid * 8 + (lane >> 3);
    const int uA = (lane & 7) ^ (lane >> 3);
    const int srcA = rA * 64 + uA * 8;   // element offset within chunk

#define PREFETCH(CH, BUF)                                                      \
    {                                                                          \
        gload_lds16(emb_hi + (size_t)(CH) * 2048 + srcA, &s_hi[BUF][wid * 512]); \
        gload_lds16(emb_lo + (size_t)(CH) * 2048 + srcA, &s_lo[BUF][wid * 512]); \
    }

    // issue chunk-0 DMA first; e2 stage + A-frag loads below overlap it
    PREFETCH(0, 0);
    s_e2[t] = e2[t] + SBIAS;
    s_e2[t + 256] = e2[t + 256] + SBIAS;

    const float* xbase = x + (size_t)b * 262144 + (size_t)grp * 65536 + hwb;

    // A fragments: [mt][kt], hi and lo. 8 strided dwords each, split to bf16.
    short8 ahi[2][2], alo[2][2];
#pragma unroll
    for (int mt = 0; mt < 2; ++mt)
#pragma unroll
        for (int kt = 0; kt < 2; ++kt) {
#pragma unroll
            for (int j = 0; j < 8; ++j) {
                float xv = xbase[(kt * 32 + q * 8 + j) * 1024 + mt * 16 + c];
                short h, l; bf16split(xv, h, l);
                ahi[mt][kt][j] = h; alo[mt][kt][j] = l;
            }
        }

    unsigned best[2][4], sec[2][4];
#pragma unroll
    for (int mt = 0; mt < 2; ++mt)
#pragma unroll
        for (int r = 0; r < 4; ++r) { best[mt][r] = 0xFFFFFFFFu; sec[mt][r] = 0xFFFFFFFFu; }

    const int p8 = (q ^ (c & 7)) << 3;   // swizzled read granule (shorts)

    __syncthreads();                      // drains chunk-0 DMA + e2 stage

    int cur = 0;
    for (int ch = 0; ch < 16; ++ch) {
        if (ch < 15) PREFETCH(ch + 1, cur ^ 1);   // in flight across MFMA block
        const int C0 = ch * 32;

#pragma unroll
        for (int nt = 0; nt < 2; ++nt) {
            const int o = (nt * 16 + c) * 64 + p8;     // (r&7)==(c&7) since 16|nt*16
            short8 bh0 = *(const short8*)&s_hi[cur][o];
            short8 bh1 = *(const short8*)&s_hi[cur][o ^ 32];   // granule q+4
            short8 bl0 = *(const short8*)&s_lo[cur][o];
            short8 bl1 = *(const short8*)&s_lo[cur][o ^ 32];
            const float se2 = s_e2[C0 + nt * 16 + c];
            const unsigned n = (unsigned)(C0 + nt * 16 + c);
#pragma unroll
            for (int mt = 0; mt < 2; ++mt) {
                floatx4 a4 = (floatx4){se2, se2, se2, se2};   // C = e2+96 (codebook = -2w)
                a4 = __builtin_amdgcn_mfma_f32_16x16x32_bf16(alo[mt][0], bh0, a4, 0, 0, 0);
                a4 = __builtin_amdgcn_mfma_f32_16x16x32_bf16(ahi[mt][0], bl0, a4, 0, 0, 0);
                a4 = __builtin_amdgcn_mfma_f32_16x16x32_bf16(ahi[mt][0], bh0, a4, 0, 0, 0);
                a4 = __builtin_amdgcn_mfma_f32_16x16x32_bf16(alo[mt][1], bh1, a4, 0, 0, 0);
                a4 = __builtin_amdgcn_mfma_f32_16x16x32_bf16(ahi[mt][1], bl1, a4, 0, 0, 0);
                a4 = __builtin_amdgcn_mfma_f32_16x16x32_bf16(ahi[mt][1], bh1, a4, 0, 0, 0);
                // epilogue: packed key; ~4 VALU/candidate (and_or, min, umed3 pair)
#pragma unroll
                for (int r = 0; r < 4; ++r) {
                    unsigned key = (__float_as_uint(a4[r]) & ~511u) | n;
                    unsigned bo = best[mt][r];
                    best[mt][r] = bo < key ? bo : key;
                    unsigned mx = bo > key ? bo : key;
                    sec[mt][r]  = sec[mt][r] < mx ? sec[mt][r] : mx;
                }
            }
        }

        // single barrier/chunk: separates this chunk's reads of buf[cur] from
        // next iter's DMA into buf[cur], and completes DMA into buf[cur^1].
        __syncthreads();
        cur ^= 1;
    }

    // ---- cross-lane merge over the 16 cols; record args + near-tie flags
#pragma unroll
    for (int mt = 0; mt < 2; ++mt)
#pragma unroll
        for (int r = 0; r < 4; ++r) {
            unsigned b_ = best[mt][r], s_ = sec[mt][r];
#pragma unroll
            for (int sh = 1; sh < 16; sh <<= 1) {
                unsigned ob = (unsigned)__shfl_xor((int)b_, sh, 64);
                unsigned os = (unsigned)__shfl_xor((int)s_, sh, 64);
                unsigned mx = b_ > ob ? b_ : ob;           // 2nd-min of union
                s_ = s_ < os ? s_ : os;
                s_ = s_ < mx ? s_ : mx;
                b_ = b_ < ob ? b_ : ob;
            }
            if (c == 0) {
                int p = mt * 16 + q * 4 + r;           // 0..31 within wave
                s_arg[wid * 32 + p] = (int)(b_ & 511u);
                float fb = __uint_as_float(b_ & ~511u);
                float fs = __uint_as_float(s_ & ~511u);
                if (fs - fb <= TAUQ) {
                    int slot = atomicAdd(&s_nflag, 1); // cap 128 == positions/block
                    s_flags[slot] = wid * 32 + p;      // block-local position
                }
            }
        }

    // ---- result output: wave's 32 positions (same-wave s_arg, no barrier)
    {
        int p = lane & 31, gi = lane >> 5;
        int ac = s_arg[wid * 32 + p];
        const float* ev = embT + (size_t)ac * GDIM;
        float* rp = out_res + (size_t)b * 262144 + (size_t)grp * 65536 + hwb + p;
#pragma unroll
        for (int it = 0; it < 32; ++it) {
            int g = it * 2 + gi;
            rp[(size_t)g * 1024] = ev[g] * 0.5f;
        }
    }

    __syncthreads();
    // ---- argmin output: block's 128 positions, one coalesced pass
    if (t < 128) {
        int bp = ((blk & 511) << 7) + t;
        out_arg[(size_t)(bp >> 10) * 4096 + (size_t)grp * 1024 + (bp & 1023)] =
            (float)s_arg[t];
    }
    __syncthreads();   // out_arg/out_res drained before fix may overwrite

    // ---- exact f64 fix of this block's flagged positions (typ. 0-2)
    const int nf = s_nflag;
    for (int f = wid; f < nf; f += 4) {
        const int hwa = s_flags[f];                 // block-local 0..127
        const int pos = ((blk & 511) << 7) + hwa;   // position within (grp) slab
        const int fb = pos >> 10;
        const int sidx = pos & 1023;
        // stage x-vector to LDS (lane = dim); same-wave RAW
        s_fixx[wid][lane] =
            x[(size_t)fb * 262144 + (size_t)grp * 65536 + (size_t)lane * 1024 + sidx];
        asm volatile("s_waitcnt lgkmcnt(0)" ::: "memory");

        double bd = DBL_MAX; int bk = 0;
        for (int m = 0; m < KCODES / 64; ++m) {
            const int k = lane + m * 64;
            const float* er = embT + (size_t)k * GDIM;
            double dot = 0.0;
#pragma unroll 4
            for (int g = 0; g < GDIM; g += 4) {
                float4 e4 = *(const float4*)(er + g);
                float4 xv = *(const float4*)&s_fixx[wid][g];   // broadcast read
                dot += (double)xv.x * (double)e4.x;
                dot += (double)xv.y * (double)e4.y;
                dot += (double)xv.z * (double)e4.z;
                dot += (double)xv.w * (double)e4.w;
            }
            double s = e2d[k] - 2.0 * dot;
            if (s < bd) { bd = s; bk = k; }            // ascending k per lane
        }
        for (int off = 32; off > 0; off >>= 1) {       // lexicographic (s, k)
            double od = __shfl_down(bd, off, 64);
            int    ok = __shfl_down(bk, off, 64);
            if (od < bd || (od == bd && ok < bk)) { bd = od; bk = ok; }
        }
        bk = __shfl(bk, 0, 64);

        if (lane == 0)
            out_arg[(size_t)fb * 4096 + (size_t)grp * 1024 + sidx] = (float)bk;
        out_res[(size_t)fb * 262144 + (size_t)grp * 65536 + (size_t)lane * 1024 + sidx] =
            embT[(size_t)bk * GDIM + lane] * 0.5f;
    }
#undef PREFETCH
}

extern "C" void kernel_launch(void* const* d_in, const int* in_sizes, int n_in,
                              void* d_out, int out_size, void* d_ws, size_t ws_size,
                              hipStream_t stream) {
    const float* x = (const float*)d_in[0];      // (64,256,32,32) f32
    const float* w = (const float*)d_in[1];      // (64,512) f32
    float* out_res = (float*)d_out;              // 16777216 floats
    float* out_arg = (float*)d_out + 16777216;   // 262144 floats

    float*    embT   = (float*)d_ws;
    float*    e2     = embT + 32768;
    double*   e2d    = (double*)((char*)d_ws + (size_t)33280 * 4);
    short*    emb_hi = (short*)((float*)d_ws + 34304);
    short*    emb_lo = (short*)((float*)d_ws + 50688);

    prep_kernel<<<128, 256, 0, stream>>>(w, embT, e2, e2d, emb_hi, emb_lo);
    vq_kernel<<<2048, 256, 0, stream>>>(x, embT, e2, e2d, emb_hi, emb_lo,
                                        out_res, out_arg);
}